// Round 16
// baseline (35.374 us; speedup 1.0000x reference)
//
#include <hip/hip_runtime.h>
#include <hip/hip_fp16.h>
#include <math.h>

#define A 5
#define S 1024
#define T 1024
#define KCH 8
#define B0 128
#define L 8192
#define NPROB 1000
#define EPSF 1e-12f
#define CHUNK 8                // time steps per lane
#define PPB 2                  // pairs per block (2 waves each -> 256 threads)
#define PFSCALE 32.0f          // pf u16 fixed-point: [-2048, 0], step 1/32
#define PFINV 0.03125f
#define PCSCALE 65535.0f       // pcor u16 fixed-point on [0,1]
#define PCINV (1.0f / 65535.0f)

__device__ __forceinline__ float sigmoidf_(float x) {
    return 1.0f / (1.0f + __expf(-x));
}

// K1: BKT forward filter via wave-parallel 2x2-matrix scan. (R14 structure;
// problem/correct loads hoisted ABOVE the exp-table build so HBM latency
// hides under the 1000-exp construction instead of stalling after the barrier.)
// Emits ONE packed uint per slot:
//   [31:16] -pf_local * 32 (u16)   [15:0] pcor * 65535 (u16; 0xFFFF = padding)
__global__ __launch_bounds__(256) void bkt_filter_kernel(
    const float* __restrict__ dyn_logits,   // [50][3]
    const float* __restrict__ obs_kc,       // [50][2]
    const float* __restrict__ obs_prob,     // [1000][2]
    const float* __restrict__ abil,         // [5]
    const int*   __restrict__ trial,        // [S][T]
    const int*   __restrict__ problem,      // [S][T]
    const int*   __restrict__ correct,      // [S][T]
    const int*   __restrict__ kc,           // [S]
    unsigned* __restrict__ slot4,           // [A][S][T] packed
    float* __restrict__ sumchunk)           // [A][B0][KCH]
{
    __shared__ float2 s_e[NPROB];           // 8 KB: (exp(-op0), exp(+op1))
    __shared__ float  s_m0[PPB][4];         // wave-0 total chunk matrix
    __shared__ float  s_llw[PPB];           // wave-0 total obs-ll

    int wv = threadIdx.x >> 6;
    int lane = threadIdx.x & 63;
    int pib = wv >> 1;                      // pair within block
    int half = wv & 1;                      // which T/2 half this wave owns
    int pair = blockIdx.x * PPB + pib;      // < A*S
    int a = pair >> 10;
    int s = pair & (S - 1);
    int t0 = half * (T / 2) + lane * CHUNK;

    // ---- issue HBM loads FIRST; they complete under the table build ----
    const int4* pv4 = (const int4*)(problem + (size_t)s * T + t0);
    const int4* cv4 = (const int4*)(correct + (size_t)s * T + t0);
    int4 pva = pv4[0], pvb = pv4[1];
    int4 cva = cv4[0], cvb = cv4[1];
    int kcs = kc[s];
    float ability = abil[a];

    for (int i = threadIdx.x; i < NPROB; i += 256) {
        float2 op = ((const float2*)obs_prob)[i];
        s_e[i] = make_float2(__expf(-op.x), __expf(op.y));
    }
    __syncthreads();

    float pL = sigmoidf_(dyn_logits[kcs * 3 + 0]);
    float pF = sigmoidf_(dyn_logits[kcs * 3 + 1]);
    float pI = sigmoidf_(dyn_logits[kcs * 3 + 2]);
    float ok0 = obs_kc[kcs * 2 + 0];
    float ok1 = obs_kc[kcs * 2 + 1];
    float t00 = 1.0f - pL, t01 = pF, t10 = pL, t11 = 1.0f - pF;
    float c0 = __expf(-ok0 - ability);      // pc0 = rcp(1 + e.x*c0)
    float c1 = __expf( ok1 - ability);      // pc1 = rcp(1 + e.y*c1)

    int pj[8] = {pva.x, pva.y, pva.z, pva.w, pvb.x, pvb.y, pvb.z, pvb.w};
    int cj[8] = {cva.x, cva.y, cva.z, cva.w, cvb.x, cvb.y, cvb.z, cvb.w};
    int cmask = 0, vmask = 0xFF;            // lower half: always valid (len>=896)
    #pragma unroll
    for (int j = 0; j < 8; ++j)
        cmask |= (cj[j] & 1) << j;
    if (half == 1) {
        const int4* tv4 = (const int4*)(trial + (size_t)s * T + t0);
        int4 tva = tv4[0], tvb = tv4[1];
        int vj[8] = {tva.x, tva.y, tva.z, tva.w, tvb.x, tvb.y, tvb.z, tvb.w};
        vmask = 0;
        #pragma unroll
        for (int j = 0; j < 8; ++j)
            vmask |= (vj[j] != -1) << j;
    }

    // ---- Phase 1: per-lane chunk matrix product (single renorm at end) ----
    float pc0a[8], pc1a[8];
    float p00 = 1.0f, p01 = 0.0f, p10 = 0.0f, p11 = 1.0f;
    #pragma unroll
    for (int j = 0; j < 8; ++j) {
        float2 e = s_e[pj[j]];
        float pc0 = __builtin_amdgcn_rcpf(1.0f + e.x * c0);
        float pc1 = __builtin_amdgcn_rcpf(1.0f + e.y * c1);
        pc0a[j] = pc0; pc1a[j] = pc1;
        bool c = (cmask >> j) & 1;
        float lik0 = c ? pc0 : 1.0f - pc0;
        float lik1 = c ? pc1 : 1.0f - pc1;
        float r0 = lik0 * p00, r1 = lik1 * p10;
        float r2 = lik0 * p01, r3 = lik1 * p11;
        p00 = t00 * r0 + t01 * r1;
        p10 = t10 * r0 + t11 * r1;
        p01 = t00 * r2 + t01 * r3;
        p11 = t10 * r2 + t11 * r3;
        if (j == 7) {
            float inv = __builtin_amdgcn_rcpf(fmaxf(p00 + p01 + p10 + p11, 1e-30f));
            p00 *= inv; p01 *= inv; p10 *= inv; p11 *= inv;
        }
    }

    // ---- Phase 2a: intra-wave inclusive matrix scan (renorm at 2 levels) ----
    float q00 = p00, q01 = p01, q10 = p10, q11 = p11;
    #pragma unroll
    for (int off = 1; off < 64; off <<= 1) {
        float o00 = __shfl_up(q00, off);
        float o01 = __shfl_up(q01, off);
        float o10 = __shfl_up(q10, off);
        float o11 = __shfl_up(q11, off);
        if (lane >= off) {
            float n00 = q00 * o00 + q01 * o10;
            float n01 = q00 * o01 + q01 * o11;
            float n10 = q10 * o00 + q11 * o10;
            float n11 = q10 * o01 + q11 * o11;
            q00 = n00; q01 = n01; q10 = n10; q11 = n11;
        }
        if (off == 8 || off == 32) {
            float inv = __builtin_amdgcn_rcpf(fmaxf(q00 + q01 + q10 + q11, 1e-30f));
            q00 *= inv; q01 *= inv; q10 *= inv; q11 *= inv;
        }
    }
    if (half == 0 && lane == 63) {
        float inv = __builtin_amdgcn_rcpf(fmaxf(q00 + q01 + q10 + q11, 1e-30f));
        s_m0[pib][0] = q00 * inv; s_m0[pib][1] = q01 * inv;
        s_m0[pib][2] = q10 * inv; s_m0[pib][3] = q11 * inv;
    }
    __syncthreads();

    // ---- Phase 2b: exclusive prefix, normalize, cross-wave compose ----
    float e00 = __shfl_up(q00, 1), e01 = __shfl_up(q01, 1);
    float e10 = __shfl_up(q10, 1), e11 = __shfl_up(q11, 1);
    if (lane == 0) { e00 = 1.0f; e01 = 0.0f; e10 = 0.0f; e11 = 1.0f; }
    {
        float inv = __builtin_amdgcn_rcpf(fmaxf(e00 + e01 + e10 + e11, 1e-30f));
        e00 *= inv; e01 *= inv; e10 *= inv; e11 *= inv;
    }
    if (half == 1) {
        float m00 = s_m0[pib][0], m01 = s_m0[pib][1];
        float m10 = s_m0[pib][2], m11 = s_m0[pib][3];
        float n00 = e00 * m00 + e01 * m10;
        float n01 = e00 * m01 + e01 * m11;
        float n10 = e10 * m00 + e11 * m10;
        float n11 = e10 * m01 + e11 * m11;
        e00 = n00; e01 = n01; e10 = n10; e11 = n11;
    }
    float a0 = e00 * (1.0f - pI) + e01 * pI;
    float a1 = e10 * (1.0f - pI) + e11 * pI;
    {
        float inv = __builtin_amdgcn_rcpf(fmaxf(a0 + a1, EPSF));
        a0 *= inv; a1 *= inv;
    }

    // ---- Phase 3: replay with unnormalized alpha (no renorm; min ~2.6e-23) ----
    float ll[8];
    float pcs[8];
    float llsum = 0.0f;
    #pragma unroll
    for (int j = 0; j < 8; ++j) {
        float pc0 = pc0a[j], pc1 = pc1a[j];
        bool c = (cmask >> j) & 1;
        bool valid = (vmask >> j) & 1;
        float num = a0 * pc0 + a1 * pc1;
        float den = a0 + a1;
        float pcor = num * __builtin_amdgcn_rcpf(den);
        float p0v = 1.0f - pcor;
        float py = c ? pcor : p0v;
        float llj = valid ? __logf(fmaxf(py, EPSF)) : 0.0f;
        ll[j] = llj; llsum += llj;
        pcs[j] = valid ? pcor : 1.0f;       // 1.0 marks padding (-> 0xFFFF)
        float lik0 = c ? pc0 : 1.0f - pc0;
        float lik1 = c ? pc1 : 1.0f - pc1;
        float q0 = a0 * lik0, q1 = a1 * lik1;
        a0 = q0 * t00 + q1 * t01;
        a1 = q0 * t10 + q1 * t11;
    }

    // ---- obs-ll scan: intra-wave + cross-wave base ----
    float incl = llsum;
    #pragma unroll
    for (int off = 1; off < 64; off <<= 1) {
        float o = __shfl_up(incl, off);
        if (lane >= off) incl += o;
    }
    float excl = incl - llsum;
    if (half == 0 && lane == 63) s_llw[pib] = incl;
    __syncthreads();
    int b = s >> 3, chunk = s & 7;
    if (half == 1) {
        float w0 = s_llw[pib];
        excl += w0;
        if (lane == 63)
            sumchunk[((size_t)a * B0 + b) * KCH + chunk] = w0 + incl;
    }

    // ---- packed write: (pf_u16 << 16) | pcor_u16, 2x uint4 per lane ----
    unsigned w[8];
    float run = excl;
    #pragma unroll
    for (int j = 0; j < 8; ++j) {
        unsigned pu  = (unsigned)(pcs[j] * PCSCALE + 0.5f);
        unsigned pfu = (unsigned)(fminf(65535.0f, -run * PFSCALE) + 0.5f);
        w[j] = (pfu << 16) | pu;
        run += ll[j];
    }
    unsigned* sp = slot4 + (size_t)pair * T + t0;
    ((uint4*)sp)[0] = make_uint4(w[0], w[1], w[2], w[3]);
    ((uint4*)sp)[1] = make_uint4(w[4], w[5], w[6], w[7]);
}

// K3: one block per (subsequence, half) = 2048 blocks, 2 slots/thread.
__global__ __launch_bounds__(256) void combine_kernel(
    const unsigned* __restrict__ slot4,       // [A][S][T] packed
    const float* __restrict__ sumchunk,       // [A][B0][KCH]
    float* __restrict__ out)                  // [B0][L][2]
{
    int bid = blockIdx.x;                 // [0, 2048)
    int s_sub = bid >> 1;                 // = b*KCH + chunk
    int h = bid & 1;
    int b = s_sub >> 3, chunk = s_sub & 7;
    int sl = h * 512 + threadIdx.x * 2;   // slot within chunk

    float pf[A][2];
    float p1v[A][2], p0v[A][2];
    #pragma unroll
    for (int a = 0; a < A; ++a) {
        const float* scp = sumchunk + ((size_t)a * B0 + b) * KCH;
        float4 ca = ((const float4*)scp)[0];
        float4 cb = ((const float4*)scp)[1];
        float cs[8] = {ca.x, ca.y, ca.z, ca.w, cb.x, cb.y, cb.z, cb.w};
        float base = 0.0f;
        #pragma unroll
        for (int k = 0; k < 8; ++k) base += (k < chunk) ? cs[k] : 0.0f;
        size_t off = ((size_t)a * S + s_sub) * T + sl;
        uint2 q = *(const uint2*)(slot4 + off);
        unsigned uu[2] = {q.x, q.y};
        #pragma unroll
        for (int j = 0; j < 2; ++j) {
            unsigned pu = uu[j] & 0xFFFFu;
            float p1 = (float)pu * PCINV;
            p1v[a][j] = p1;
            p0v[a][j] = (pu == 0xFFFFu) ? 1.0f : 1.0f - p1;
            pf[a][j] = base - PFINV * (float)(uu[j] >> 16);
        }
    }

    float o[4];
    #pragma unroll
    for (int j = 0; j < 2; ++j) {
        float pm = -INFINITY;
        #pragma unroll
        for (int a = 0; a < A; ++a) pm = fmaxf(pm, pf[a][j]);
        float Se = 0.0f, S0 = 0.0f, S1 = 0.0f;
        #pragma unroll
        for (int a = 0; a < A; ++a) {
            float e = __expf(pf[a][j] - pm);
            Se += e;
            S0 += e * p0v[a][j];
            S1 += e * p1v[a][j];
        }
        float ls = __logf(Se);
        o[2*j]   = __logf(S0) - ls;
        o[2*j+1] = __logf(S1) - ls;
    }
    float* op = out + 2 * ((size_t)b * L + chunk * T + sl);
    *(float4*)op = make_float4(o[0], o[1], o[2], o[3]);
}

extern "C" void kernel_launch(void* const* d_in, const int* in_sizes, int n_in,
                              void* d_out, int out_size, void* d_ws, size_t ws_size,
                              hipStream_t stream) {
    const float* dyn  = (const float*)d_in[0];
    const float* okc  = (const float*)d_in[1];
    const float* oprb = (const float*)d_in[2];
    const float* ab   = (const float*)d_in[3];
    const int* trial  = (const int*)d_in[4];
    const int* prob   = (const int*)d_in[5];
    const int* corr   = (const int*)d_in[6];
    const int* kc     = (const int*)d_in[7];
    float* out = (float*)d_out;

    char* wsp = (char*)d_ws;
    unsigned* slot4 = (unsigned*)wsp;                               // 21 MB
    float* sumchunk = (float*)(wsp + (size_t)A * S * T * 4);        // 20 KB

    bkt_filter_kernel<<<(A * S) / PPB, 256, 0, stream>>>(
        dyn, okc, oprb, ab, trial, prob, corr, kc, slot4, sumchunk);
    combine_kernel<<<2 * B0 * KCH, 256, 0, stream>>>(slot4, sumchunk, out);
}

// Round 17
// 33.140 us; speedup vs baseline: 1.0674x; 1.0674x over previous
//
#include <hip/hip_runtime.h>
#include <hip/hip_fp16.h>
#include <math.h>

#define A 5
#define S 1024
#define T 1024
#define KCH 8
#define B0 128
#define L 8192
#define NPROB 1000
#define EPSF 1e-12f
#define CHUNK 8                // time steps per lane
#define PPB 2                  // pairs per block (2 waves each -> 256 threads)
#define PFSCALE 32.0f          // pf u16 fixed-point: [-2048, 0], step 1/32
#define PFINV 0.03125f
#define PCSCALE 65535.0f       // pcor u16 fixed-point on [0,1]
#define PCINV (1.0f / 65535.0f)

__device__ __forceinline__ float sigmoidf_(float x) {
    return 1.0f / (1.0f + __expf(-x));
}

// K1: BKT forward filter via wave-parallel 2x2-matrix scan. (exact R14 —
// loads NOT hoisted: keeping them after the table barrier stays under the
// 64-VGPR occupancy cliff, worth more than the latency overlap.)
// Emits ONE packed uint per slot:
//   [31:16] -pf_local * 32 (u16)   [15:0] pcor * 65535 (u16; 0xFFFF = padding)
__global__ __launch_bounds__(256) void bkt_filter_kernel(
    const float* __restrict__ dyn_logits,   // [50][3]
    const float* __restrict__ obs_kc,       // [50][2]
    const float* __restrict__ obs_prob,     // [1000][2]
    const float* __restrict__ abil,         // [5]
    const int*   __restrict__ trial,        // [S][T]
    const int*   __restrict__ problem,      // [S][T]
    const int*   __restrict__ correct,      // [S][T]
    const int*   __restrict__ kc,           // [S]
    unsigned* __restrict__ slot4,           // [A][S][T] packed
    float* __restrict__ sumchunk)           // [A][B0][KCH]
{
    __shared__ float2 s_e[NPROB];           // 8 KB: (exp(-op0), exp(+op1))
    __shared__ float  s_m0[PPB][4];         // wave-0 total chunk matrix
    __shared__ float  s_llw[PPB];           // wave-0 total obs-ll

    for (int i = threadIdx.x; i < NPROB; i += 256) {
        float2 op = ((const float2*)obs_prob)[i];
        s_e[i] = make_float2(__expf(-op.x), __expf(op.y));
    }
    __syncthreads();

    int wv = threadIdx.x >> 6;
    int lane = threadIdx.x & 63;
    int pib = wv >> 1;                      // pair within block
    int half = wv & 1;                      // which T/2 half this wave owns
    int pair = blockIdx.x * PPB + pib;      // < A*S
    int a = pair >> 10;
    int s = pair & (S - 1);

    float ability = abil[a];
    int kcs = kc[s];
    float pL = sigmoidf_(dyn_logits[kcs * 3 + 0]);
    float pF = sigmoidf_(dyn_logits[kcs * 3 + 1]);
    float pI = sigmoidf_(dyn_logits[kcs * 3 + 2]);
    float ok0 = obs_kc[kcs * 2 + 0];
    float ok1 = obs_kc[kcs * 2 + 1];
    float t00 = 1.0f - pL, t01 = pF, t10 = pL, t11 = 1.0f - pF;
    float c0 = __expf(-ok0 - ability);      // pc0 = rcp(1 + e.x*c0)
    float c1 = __expf( ok1 - ability);      // pc1 = rcp(1 + e.y*c1)

    int t0 = half * (T / 2) + lane * CHUNK;
    const int4* pv4 = (const int4*)(problem + (size_t)s * T + t0);
    const int4* cv4 = (const int4*)(correct + (size_t)s * T + t0);
    int4 pva = pv4[0], pvb = pv4[1];
    int4 cva = cv4[0], cvb = cv4[1];

    int pj[8] = {pva.x, pva.y, pva.z, pva.w, pvb.x, pvb.y, pvb.z, pvb.w};
    int cj[8] = {cva.x, cva.y, cva.z, cva.w, cvb.x, cvb.y, cvb.z, cvb.w};
    int cmask = 0, vmask = 0xFF;            // lower half: always valid (len>=896)
    #pragma unroll
    for (int j = 0; j < 8; ++j)
        cmask |= (cj[j] & 1) << j;
    if (half == 1) {
        const int4* tv4 = (const int4*)(trial + (size_t)s * T + t0);
        int4 tva = tv4[0], tvb = tv4[1];
        int vj[8] = {tva.x, tva.y, tva.z, tva.w, tvb.x, tvb.y, tvb.z, tvb.w};
        vmask = 0;
        #pragma unroll
        for (int j = 0; j < 8; ++j)
            vmask |= (vj[j] != -1) << j;
    }

    // ---- Phase 1: per-lane chunk matrix product (single renorm at end) ----
    float pc0a[8], pc1a[8];
    float p00 = 1.0f, p01 = 0.0f, p10 = 0.0f, p11 = 1.0f;
    #pragma unroll
    for (int j = 0; j < 8; ++j) {
        float2 e = s_e[pj[j]];
        float pc0 = __builtin_amdgcn_rcpf(1.0f + e.x * c0);
        float pc1 = __builtin_amdgcn_rcpf(1.0f + e.y * c1);
        pc0a[j] = pc0; pc1a[j] = pc1;
        bool c = (cmask >> j) & 1;
        float lik0 = c ? pc0 : 1.0f - pc0;
        float lik1 = c ? pc1 : 1.0f - pc1;
        float r0 = lik0 * p00, r1 = lik1 * p10;
        float r2 = lik0 * p01, r3 = lik1 * p11;
        p00 = t00 * r0 + t01 * r1;
        p10 = t10 * r0 + t11 * r1;
        p01 = t00 * r2 + t01 * r3;
        p11 = t10 * r2 + t11 * r3;
        if (j == 7) {
            float inv = __builtin_amdgcn_rcpf(fmaxf(p00 + p01 + p10 + p11, 1e-30f));
            p00 *= inv; p01 *= inv; p10 *= inv; p11 *= inv;
        }
    }

    // ---- Phase 2a: intra-wave inclusive matrix scan (renorm at 2 levels) ----
    float q00 = p00, q01 = p01, q10 = p10, q11 = p11;
    #pragma unroll
    for (int off = 1; off < 64; off <<= 1) {
        float o00 = __shfl_up(q00, off);
        float o01 = __shfl_up(q01, off);
        float o10 = __shfl_up(q10, off);
        float o11 = __shfl_up(q11, off);
        if (lane >= off) {
            float n00 = q00 * o00 + q01 * o10;
            float n01 = q00 * o01 + q01 * o11;
            float n10 = q10 * o00 + q11 * o10;
            float n11 = q10 * o01 + q11 * o11;
            q00 = n00; q01 = n01; q10 = n10; q11 = n11;
        }
        if (off == 8 || off == 32) {
            float inv = __builtin_amdgcn_rcpf(fmaxf(q00 + q01 + q10 + q11, 1e-30f));
            q00 *= inv; q01 *= inv; q10 *= inv; q11 *= inv;
        }
    }
    if (half == 0 && lane == 63) {
        float inv = __builtin_amdgcn_rcpf(fmaxf(q00 + q01 + q10 + q11, 1e-30f));
        s_m0[pib][0] = q00 * inv; s_m0[pib][1] = q01 * inv;
        s_m0[pib][2] = q10 * inv; s_m0[pib][3] = q11 * inv;
    }
    __syncthreads();

    // ---- Phase 2b: exclusive prefix, normalize, cross-wave compose ----
    float e00 = __shfl_up(q00, 1), e01 = __shfl_up(q01, 1);
    float e10 = __shfl_up(q10, 1), e11 = __shfl_up(q11, 1);
    if (lane == 0) { e00 = 1.0f; e01 = 0.0f; e10 = 0.0f; e11 = 1.0f; }
    {
        float inv = __builtin_amdgcn_rcpf(fmaxf(e00 + e01 + e10 + e11, 1e-30f));
        e00 *= inv; e01 *= inv; e10 *= inv; e11 *= inv;
    }
    if (half == 1) {
        float m00 = s_m0[pib][0], m01 = s_m0[pib][1];
        float m10 = s_m0[pib][2], m11 = s_m0[pib][3];
        float n00 = e00 * m00 + e01 * m10;
        float n01 = e00 * m01 + e01 * m11;
        float n10 = e10 * m00 + e11 * m10;
        float n11 = e10 * m01 + e11 * m11;
        e00 = n00; e01 = n01; e10 = n10; e11 = n11;
    }
    float a0 = e00 * (1.0f - pI) + e01 * pI;
    float a1 = e10 * (1.0f - pI) + e11 * pI;
    {
        float inv = __builtin_amdgcn_rcpf(fmaxf(a0 + a1, EPSF));
        a0 *= inv; a1 *= inv;
    }

    // ---- Phase 3: replay with unnormalized alpha (no renorm; min ~2.6e-23) ----
    float ll[8];
    float pcs[8];
    float llsum = 0.0f;
    #pragma unroll
    for (int j = 0; j < 8; ++j) {
        float pc0 = pc0a[j], pc1 = pc1a[j];
        bool c = (cmask >> j) & 1;
        bool valid = (vmask >> j) & 1;
        float num = a0 * pc0 + a1 * pc1;
        float den = a0 + a1;
        float pcor = num * __builtin_amdgcn_rcpf(den);
        float p0v = 1.0f - pcor;
        float py = c ? pcor : p0v;
        float llj = valid ? __logf(fmaxf(py, EPSF)) : 0.0f;
        ll[j] = llj; llsum += llj;
        pcs[j] = valid ? pcor : 1.0f;       // 1.0 marks padding (-> 0xFFFF)
        float lik0 = c ? pc0 : 1.0f - pc0;
        float lik1 = c ? pc1 : 1.0f - pc1;
        float q0 = a0 * lik0, q1 = a1 * lik1;
        a0 = q0 * t00 + q1 * t01;
        a1 = q0 * t10 + q1 * t11;
    }

    // ---- obs-ll scan: intra-wave + cross-wave base ----
    float incl = llsum;
    #pragma unroll
    for (int off = 1; off < 64; off <<= 1) {
        float o = __shfl_up(incl, off);
        if (lane >= off) incl += o;
    }
    float excl = incl - llsum;
    if (half == 0 && lane == 63) s_llw[pib] = incl;
    __syncthreads();
    int b = s >> 3, chunk = s & 7;
    if (half == 1) {
        float w0 = s_llw[pib];
        excl += w0;
        if (lane == 63)
            sumchunk[((size_t)a * B0 + b) * KCH + chunk] = w0 + incl;
    }

    // ---- packed write: (pf_u16 << 16) | pcor_u16, 2x uint4 per lane ----
    unsigned w[8];
    float run = excl;
    #pragma unroll
    for (int j = 0; j < 8; ++j) {
        unsigned pu  = (unsigned)(pcs[j] * PCSCALE + 0.5f);
        unsigned pfu = (unsigned)(fminf(65535.0f, -run * PFSCALE) + 0.5f);
        w[j] = (pfu << 16) | pu;
        run += ll[j];
    }
    unsigned* sp = slot4 + (size_t)pair * T + t0;
    ((uint4*)sp)[0] = make_uint4(w[0], w[1], w[2], w[3]);
    ((uint4*)sp)[1] = make_uint4(w[4], w[5], w[6], w[7]);
}

// K3: one block per (subsequence, half) = 2048 blocks, 2 slots/thread.
__global__ __launch_bounds__(256) void combine_kernel(
    const unsigned* __restrict__ slot4,       // [A][S][T] packed
    const float* __restrict__ sumchunk,       // [A][B0][KCH]
    float* __restrict__ out)                  // [B0][L][2]
{
    int bid = blockIdx.x;                 // [0, 2048)
    int s_sub = bid >> 1;                 // = b*KCH + chunk
    int h = bid & 1;
    int b = s_sub >> 3, chunk = s_sub & 7;
    int sl = h * 512 + threadIdx.x * 2;   // slot within chunk

    float pf[A][2];
    float p1v[A][2], p0v[A][2];
    #pragma unroll
    for (int a = 0; a < A; ++a) {
        const float* scp = sumchunk + ((size_t)a * B0 + b) * KCH;
        float4 ca = ((const float4*)scp)[0];
        float4 cb = ((const float4*)scp)[1];
        float cs[8] = {ca.x, ca.y, ca.z, ca.w, cb.x, cb.y, cb.z, cb.w};
        float base = 0.0f;
        #pragma unroll
        for (int k = 0; k < 8; ++k) base += (k < chunk) ? cs[k] : 0.0f;
        size_t off = ((size_t)a * S + s_sub) * T + sl;
        uint2 q = *(const uint2*)(slot4 + off);
        unsigned uu[2] = {q.x, q.y};
        #pragma unroll
        for (int j = 0; j < 2; ++j) {
            unsigned pu = uu[j] & 0xFFFFu;
            float p1 = (float)pu * PCINV;
            p1v[a][j] = p1;
            p0v[a][j] = (pu == 0xFFFFu) ? 1.0f : 1.0f - p1;
            pf[a][j] = base - PFINV * (float)(uu[j] >> 16);
        }
    }

    float o[4];
    #pragma unroll
    for (int j = 0; j < 2; ++j) {
        float pm = -INFINITY;
        #pragma unroll
        for (int a = 0; a < A; ++a) pm = fmaxf(pm, pf[a][j]);
        float Se = 0.0f, S0 = 0.0f, S1 = 0.0f;
        #pragma unroll
        for (int a = 0; a < A; ++a) {
            float e = __expf(pf[a][j] - pm);
            Se += e;
            S0 += e * p0v[a][j];
            S1 += e * p1v[a][j];
        }
        float ls = __logf(Se);
        o[2*j]   = __logf(S0) - ls;
        o[2*j+1] = __logf(S1) - ls;
    }
    float* op = out + 2 * ((size_t)b * L + chunk * T + sl);
    *(float4*)op = make_float4(o[0], o[1], o[2], o[3]);
}

extern "C" void kernel_launch(void* const* d_in, const int* in_sizes, int n_in,
                              void* d_out, int out_size, void* d_ws, size_t ws_size,
                              hipStream_t stream) {
    const float* dyn  = (const float*)d_in[0];
    const float* okc  = (const float*)d_in[1];
    const float* oprb = (const float*)d_in[2];
    const float* ab   = (const float*)d_in[3];
    const int* trial  = (const int*)d_in[4];
    const int* prob   = (const int*)d_in[5];
    const int* corr   = (const int*)d_in[6];
    const int* kc     = (const int*)d_in[7];
    float* out = (float*)d_out;

    char* wsp = (char*)d_ws;
    unsigned* slot4 = (unsigned*)wsp;                               // 21 MB
    float* sumchunk = (float*)(wsp + (size_t)A * S * T * 4);        // 20 KB

    bkt_filter_kernel<<<(A * S) / PPB, 256, 0, stream>>>(
        dyn, okc, oprb, ab, trial, prob, corr, kc, slot4, sumchunk);
    combine_kernel<<<2 * B0 * KCH, 256, 0, stream>>>(slot4, sumchunk, out);
}